// Round 11
// baseline (349.709 us; speedup 1.0000x reference)
//
#include <hip/hip_runtime.h>
#include <hip/hip_bf16.h>
#include <stdint.h>
#include <stddef.h>

typedef __bf16 bf16_t;
typedef __bf16 bf16x4 __attribute__((ext_vector_type(4)));
typedef __bf16 bf16x8 __attribute__((ext_vector_type(8)));
typedef float floatx4 __attribute__((ext_vector_type(4)));

#define NN 20000
#define EE 320000
#define DD 512
#define CAP 96
#define BETA1 0.6931471805599453f
#define BETA2 0.40546510810816444f

// async global->LDS, 16B per lane. LDS dest must be wave-uniform base + lane*16.
__device__ __forceinline__ void gload16(const bf16_t* g, bf16_t* l) {
  __builtin_amdgcn_global_load_lds((const __attribute__((address_space(1))) uint32_t*)g,
                                   (__attribute__((address_space(3))) uint32_t*)l, 16, 0, 0);
}

// ------- bucket fill with degree count: esrc[dst*CAP + cnt[dst]++] = src -----
__global__ __launch_bounds__(256) void bucket_kernel(
    const int* __restrict__ src, const int* __restrict__ dst,
    int* __restrict__ cnt, int* __restrict__ esrc, int E) {
  int e = blockIdx.x * 256 + threadIdx.x;
  if (e < E) {
    int d = dst[e];
    int pos = atomicAdd(&cnt[d], 1);
    if (pos < CAP) esrc[d * CAP + pos] = src[e];
  }
}

// ---------------- fused prep: zeroing + all weight/input reformats -----------
// sections by blockIdx:
//   [0, 5000)        featb: feat f32 row-major -> bf16 row-major (8 elem/thr)
//   [5000, 5128)     BW0:   fc_w f32 [n][k] -> bf16 row-major (= B^T layout)
//   [5128, 5640)     BT1:   [w1_1; 0.1*w2_1]^T via LDS 32x33 tile transpose
//                    (round-10's strided scalar gather was 64 lines/wave-instr;
//                     this is coalesced on both sides — round-0 verified body)
//   [5640, 6152)     BT2:   [w1_2; 0.1*w2_2]^T same
//   [6152, 6231)     cnt zero
//   [6231, 8106)     esrc zero (int4) — padding slots read 0 (valid node) so
//                    the aggregate ring can ALWAYS issue its gathers (fixed
//                    vmcnt counts); add-guards drop their contribution.
// 0.1 folded into the W2 half so Acat holds RAW h:
//   [f,h] @ [W1; 0.1W2]^T = f@W1 + 0.1*(h@W2)
#define PREP_BLOCKS 8106
__global__ __launch_bounds__(256) void prep_kernel(
    const float* __restrict__ feat, const float* __restrict__ fc_w,
    const float* __restrict__ w1_1, const float* __restrict__ w2_1,
    const float* __restrict__ w1_2, const float* __restrict__ w2_2,
    bf16_t* __restrict__ featb, bf16_t* __restrict__ bw0,
    bf16_t* __restrict__ bt1, bf16_t* __restrict__ bt2,
    int* __restrict__ cnt, int* __restrict__ esrc) {
  __shared__ bf16_t tile[32][33];
  int b = blockIdx.x, t = threadIdx.x;
  if (b < 5128) {
    // straight cvt, 8 f32 -> bf16x8 per thread
    const float* in = (b < 5000) ? feat : fc_w;
    bf16_t* out = (b < 5000) ? featb : bw0;
    size_t c = (size_t)(b < 5000 ? b : b - 5000) * 256 + t;
    const float* s = in + c * 8;
    float4 v0 = *(const float4*)s, v1 = *(const float4*)(s + 4);
    bf16x8 o = {(bf16_t)v0.x, (bf16_t)v0.y, (bf16_t)v0.z, (bf16_t)v0.w,
                (bf16_t)v1.x, (bf16_t)v1.y, (bf16_t)v1.z, (bf16_t)v1.w};
    *(bf16x8*)(out + c * 8) = o;
  } else if (b < 6152) {
    // BT[n][k] = scale * W[k][n] via LDS tile; 512 blocks per BT (16 x 32).
    int base = (b < 5640) ? 5128 : 5640;
    const float* Wa = (b < 5640) ? w1_1 : w1_2;
    const float* Wb = (b < 5640) ? w2_1 : w2_2;
    bf16_t* bt = (b < 5640) ? bt1 : bt2;
    int bb = b - base;
    int n0 = (bb & 15) * 32;          // n tile
    int k0 = (bb >> 4) * 32;          // k tile, [0,1024)
    int tx = t & 31, ty = t >> 5;     // 32 x 8
    const float* W = (k0 < 512) ? Wa : Wb;
    float sc = (k0 < 512) ? 1.0f : 0.1f;
    int kk = k0 & 511;
#pragma unroll
    for (int i = 0; i < 32; i += 8)
      tile[ty + i][tx] = (bf16_t)(sc * W[(size_t)(kk + ty + i) * 512 + n0 + tx]);
    __syncthreads();
#pragma unroll
    for (int i = 0; i < 32; i += 8)
      bt[(size_t)(n0 + ty + i) * 1024 + k0 + tx] = tile[tx][ty + i];
  } else if (b < 6231) {
    int i = (b - 6152) * 256 + t;
    if (i < NN) cnt[i] = 0;
  } else {
    int i = (b - 6231) * 256 + t;     // 480000 int4 = NN*CAP ints exactly
    ((int4*)esrc)[i] = make_int4(0, 0, 0, 0);
  }
}

// ---------- bucket aggregate: one wave per dst node, LDS-DMA gather ring -----
// f = 0.9 * rsqrt(deg[node]) * sum_e hs[src_e]        (hs pre-scaled by nrm)
// Acat[node][0:512] = bf16(f)   (h-half of Acat untouched, layer-invariant)
// Round 11: 3-buffer ring, TWO chunk-gathers permanently in flight (round-10's
// 1-deep ring covered ~300cy vs 350-500cy L2/L3 gather latency). Steady-state
// outstanding (issue order) = ring(c)(4) | idx(c+2)(1) | ring(c+1)(4) = 9.
// Loop: vmcnt(4) retires ring(c)+idx(c+2) -> issue idx(c+3) + ring(c+2)
// -> consume ring(c) (landed). Fixed-count fencing: every VMEM op in the loop
// is part of the counted pattern; issues are never guarded out (offsets
// clamped, esrc zero-padded); add-guards keep the math exact.
__global__ __launch_bounds__(256) void aggregate_kernel(
    const bf16_t* __restrict__ hs, const int* __restrict__ cnt,
    const int* __restrict__ esrc, bf16_t* __restrict__ Acat) {
  __shared__ bf16_t ring[4][3][4][512];   // 4 waves x 3 bufs x 4 slots x 1KB = 48KB
  const int w = threadIdx.x >> 6;
  const int lane = threadIdx.x & 63;
  const int node = blockIdx.x * 4 + w;    // grid 5000 x 4 waves = 20000 exact
  const int* eb = esrc + (size_t)node * CAP;
  int ncnt = cnt[node];
  int n_e = ncnt < CAP ? ncnt : CAP;
  float nd = 0.9f * rsqrtf(fmaxf((float)ncnt, 1.0f));
  int nchunks = (n_e + 3) >> 2;

  float acc[8] = {};
  bf16_t* rb0 = &ring[w][0][0][lane * 8];
  bf16_t* rb1 = &ring[w][1][0][lane * 8];
  bf16_t* rb2 = &ring[w][2][0][lane * 8];

  // prologue: establish invariant with idx0/idx1 resolved serially
  asm volatile("s_waitcnt vmcnt(0)" ::: "memory");   // cnt load retired
  __builtin_amdgcn_sched_barrier(0);
  int4 i0 = *(const int4*)(eb);                      // idx(0)
  asm volatile("s_waitcnt vmcnt(0)" ::: "memory");
  __builtin_amdgcn_sched_barrier(0);
  int4 i1 = *(const int4*)(eb + 4);                  // idx(1)
  asm volatile("s_waitcnt vmcnt(0)" ::: "memory");
  __builtin_amdgcn_sched_barrier(0);
  // issue order: ring(0) x4, idx(2) x1, ring(1) x4  -> outstanding 9
  gload16(hs + (size_t)i0.x * DD + lane * 8, rb0);
  gload16(hs + (size_t)i0.y * DD + lane * 8, rb0 + 512);
  gload16(hs + (size_t)i0.z * DD + lane * 8, rb0 + 1024);
  gload16(hs + (size_t)i0.w * DD + lane * 8, rb0 + 1536);
  int4 inext = *(const int4*)(eb + 8);               // idx(2)
  gload16(hs + (size_t)i1.x * DD + lane * 8, rb1);
  gload16(hs + (size_t)i1.y * DD + lane * 8, rb1 + 512);
  gload16(hs + (size_t)i1.z * DD + lane * 8, rb1 + 1024);
  gload16(hs + (size_t)i1.w * DD + lane * 8, rb1 + 1536);

  for (int c = 0; c < nchunks; ++c) {
    // retire ring(c) + idx(c+2); keep ring(c+1) (4) in flight
    asm volatile("s_waitcnt vmcnt(4)" ::: "memory");
    __builtin_amdgcn_sched_barrier(0);
    int4 iuse = inext;                               // idx(c+2) data
    int off = (c + 3) * 4; off = off > CAP - 4 ? CAP - 4 : off;
    inext = *(const int4*)(eb + off);                // idx(c+3): 1 op
    bf16_t* rbn = (c % 3 == 0) ? rb2 : (c % 3 == 1) ? rb0 : rb1;  // (c+2)%3
    gload16(hs + (size_t)iuse.x * DD + lane * 8, rbn);
    gload16(hs + (size_t)iuse.y * DD + lane * 8, rbn + 512);
    gload16(hs + (size_t)iuse.z * DD + lane * 8, rbn + 1024);
    gload16(hs + (size_t)iuse.w * DD + lane * 8, rbn + 1536);
    // consume ring(c) — landed (retired by the vmcnt(4) above)
    bf16_t* rb = (c % 3 == 0) ? rb0 : (c % 3 == 1) ? rb1 : rb2;   // c%3
    bf16x8 v0 = *(const bf16x8*)(rb);
    bf16x8 v1 = *(const bf16x8*)(rb + 512);
    bf16x8 v2 = *(const bf16x8*)(rb + 1024);
    bf16x8 v3 = *(const bf16x8*)(rb + 1536);
    int e0 = c * 4;
    if (e0 < n_e) {
#pragma unroll
      for (int k = 0; k < 8; ++k) acc[k] += (float)v0[k];
    }
    if (e0 + 1 < n_e) {
#pragma unroll
      for (int k = 0; k < 8; ++k) acc[k] += (float)v1[k];
    }
    if (e0 + 2 < n_e) {
#pragma unroll
      for (int k = 0; k < 8; ++k) acc[k] += (float)v2[k];
    }
    if (e0 + 3 < n_e) {
#pragma unroll
      for (int k = 0; k < 8; ++k) acc[k] += (float)v3[k];
    }
  }

  bf16x8 ob;
#pragma unroll
  for (int k = 0; k < 8; ++k) ob[k] = (bf16_t)(nd * acc[k]);
  *(bf16x8*)(Acat + (size_t)node * 1024 + lane * 8) = ob;
}

// -------- GEMM: C = A(MxK,bf16) @ B(Kx512), B given transposed BT[n][k] ------
// Round-2 verified structure (best of 7 variants tried): tile 64x128, 4 waves
// (2x2, 32x64 each), BK=64, 2-buf LDS via global_load_lds, 1 barrier/iter,
// 48KB LDS -> 3 blocks/CU. DO NOT TOUCH (rounds 1,3,4,5,6,8 all regressed).
// Swizzle for 128B rows: stored chunk cc = global chunk gc ^ (row&7).
// XCD swizzle: bIdx = (m%8) + 8*(n + 4*(m/8)).
// MODE 0: h = acc+bias -> acat2[row*1024+512+col]=bf16(h) (raw, for f0) AND
//         outb[row*512+col] = bf16(nrm_row*h)  (hs: pre-scaled aggregate input)
// MODE 1: fs = Acat[row][col] + 0.1*Acat[row][512+col];
//         r = relu((1-beta)*fs + beta*acc + bias);
//         outb[idx] = bf16(nrm_row*r)          (res': pre-scaled agg-2 input)
// MODE 2: same r -> outf[idx] = r (f32 final output)
template <int MODE>
__global__ __launch_bounds__(256) void gemm_kernel(
    const bf16_t* __restrict__ A, const bf16_t* __restrict__ BT,
    int lda, int ldb, int K, int M,
    const float* __restrict__ bias,
    const bf16_t* __restrict__ acat_ro, float beta,
    float* __restrict__ outf, bf16_t* __restrict__ outb,
    bf16_t* __restrict__ acat2,
    const int* __restrict__ cnt) {
  __shared__ bf16_t As[2][64 * 64];    // 8 KB per buf
  __shared__ bf16_t Bs[2][128 * 64];   // 16 KB per buf

  const int bid = blockIdx.x;
  const int mt = (bid >> 5) * 8 + (bid & 7);   // m-tile
  const int nt = (bid >> 3) & 3;               // n-tile
  const int m0 = mt * 64;
  if (m0 >= M) return;
  const int n0 = nt * 128;

  const int t = threadIdx.x;
  const int lane = t & 63;
  const int w = t >> 6;
  const int wm = w & 1, wn = w >> 1;
  const int quad = lane >> 4, m16 = lane & 15;

  // staging: LDS-linear chunk c_l -> row r=c_l>>3, slot cc=c_l&7 holds global
  // chunk gc = cc ^ (r&7). Thread t stages c_l = t (+256 [+512 +768 for B]).
  const int tr = t >> 3;
  const int gc = (t & 7) ^ (tr & 7);
  int arow0 = m0 + tr;      arow0 = arow0 < M ? arow0 : M - 1;  // clamp OOB
  int arow1 = m0 + tr + 32; arow1 = arow1 < M ? arow1 : M - 1;
  const bf16_t* agp0 = A + (size_t)arow0 * lda + gc * 8;
  const bf16_t* agp1 = A + (size_t)arow1 * lda + gc * 8;
  const bf16_t* bgp0 = BT + (size_t)(n0 + tr) * ldb + gc * 8;
  const bf16_t* bgp1 = BT + (size_t)(n0 + tr + 32) * ldb + gc * 8;
  const bf16_t* bgp2 = BT + (size_t)(n0 + tr + 64) * ldb + gc * 8;
  const bf16_t* bgp3 = BT + (size_t)(n0 + tr + 96) * ldb + gc * 8;

#define STAGE(buf, ko)                              \
  gload16(agp0 + (ko), &As[buf][t * 8]);            \
  gload16(agp1 + (ko), &As[buf][(t + 256) * 8]);    \
  gload16(bgp0 + (ko), &Bs[buf][t * 8]);            \
  gload16(bgp1 + (ko), &Bs[buf][(t + 256) * 8]);    \
  gload16(bgp2 + (ko), &Bs[buf][(t + 512) * 8]);    \
  gload16(bgp3 + (ko), &Bs[buf][(t + 768) * 8]);

  floatx4 acc[2][4] = {};
  const int niter = K >> 6;

  // stage buffer 0
  STAGE(0, 0)

  for (int kt = 0; kt < niter; ++kt) {
    __syncthreads();   // drains buf kt's loads (issued one iter ago)
    const int b = kt & 1;
    if (kt + 1 < niter) {        // prefetch next buffer during compute
      const int ko = (kt + 1) * 64;
      STAGE(b ^ 1, ko)
    }

#pragma unroll
    for (int ks = 0; ks < 2; ++ks) {
      bf16x8 af[2], bfr[4];
#pragma unroll
      for (int i = 0; i < 2; ++i) {
        int arow = wm * 32 + i * 16 + m16;
        int cc = (ks * 4 + quad) ^ (arow & 7);
        af[i] = *(const bf16x8*)(&As[b][(arow * 8 + cc) * 8]);
      }
#pragma unroll
      for (int j = 0; j < 4; ++j) {
        int brow = wn * 64 + j * 16 + m16;
        int cc = (ks * 4 + quad) ^ (brow & 7);
        bfr[j] = *(const bf16x8*)(&Bs[b][(brow * 8 + cc) * 8]);
      }
#pragma unroll
      for (int i = 0; i < 2; ++i)
#pragma unroll
        for (int j = 0; j < 4; ++j)
          acc[i][j] = __builtin_amdgcn_mfma_f32_16x16x32_bf16(af[i], bfr[j], acc[i][j], 0, 0, 0);
    }
  }
#undef STAGE

  // per-thread row rsqrt(cnt) (MODE 0/1 pre-scale writes). 8 unique rows.
  float rsv[2][4];
  if constexpr (MODE != 2) {
#pragma unroll
    for (int i = 0; i < 2; ++i)
#pragma unroll
      for (int p = 0; p < 4; ++p) {
        int row = m0 + wm * 32 + i * 16 + quad * 4 + p;
        int rowc = row < M ? row : M - 1;
        rsv[i][p] = rsqrtf(fmaxf((float)cnt[rowc], 1.0f));
      }
  }

  // epilogue: C/D layout col = lane&15, row = quad*4 + reg
#pragma unroll
  for (int i = 0; i < 2; ++i) {
#pragma unroll
    for (int j = 0; j < 4; ++j) {
      int col = n0 + wn * 64 + j * 16 + m16;
      float bv = bias[col];
#pragma unroll
      for (int p = 0; p < 4; ++p) {
        int row = m0 + wm * 32 + i * 16 + quad * 4 + p;
        if (row < M) {
          float v = acc[i][j][p];
          if constexpr (MODE == 0) {
            float hv = v + bv;
            acat2[(size_t)row * 1024 + 512 + col] = (bf16_t)hv;        // raw h (f0)
            outb[(size_t)row * DD + col] = (bf16_t)(rsv[i][p] * hv);   // hs
          } else {
            size_t idx = (size_t)row * DD + col;
            float fsv = (float)acat_ro[(size_t)row * 1024 + col] +
                        0.1f * (float)acat_ro[(size_t)row * 1024 + 512 + col];
            float r = (1.0f - beta) * fsv + beta * v + bv;
            r = fmaxf(r, 0.0f);
            if constexpr (MODE == 1) outb[idx] = (bf16_t)(rsv[i][p] * r);  // res'
            else outf[idx] = r;
          }
        }
      }
    }
  }
}

extern "C" void kernel_launch(void* const* d_in, const int* in_sizes, int n_in,
                              void* d_out, int out_size, void* d_ws, size_t ws_size,
                              hipStream_t stream) {
  const float* feat = (const float*)d_in[0];
  const int* src = (const int*)d_in[1];
  const int* dst = (const int*)d_in[2];
  const float* fc_w = (const float*)d_in[3];
  const float* fc_b = (const float*)d_in[4];
  const float* w1_1 = (const float*)d_in[5];
  const float* w2_1 = (const float*)d_in[6];
  const float* b_1  = (const float*)d_in[7];
  const float* w1_2 = (const float*)d_in[8];
  const float* w2_2 = (const float*)d_in[9];
  const float* b_2  = (const float*)d_in[10];
  float* out = (float*)d_out;

  char* ws = (char*)d_ws;
  size_t off = 0;
  auto alloc = [&](size_t bytes) {
    char* p = ws + off;
    off += (bytes + 255) & ~(size_t)255;
    return p;
  };
  const size_t NDf = (size_t)NN * DD;               // 10.24M elements
  bf16_t* res_bf = (bf16_t*)alloc(NDf * sizeof(bf16_t));        // 20.48 MB (nrm*res)
  bf16_t* featb  = (bf16_t*)alloc(NDf * sizeof(bf16_t));        // 20.48 MB
  bf16_t* hs     = (bf16_t*)alloc(NDf * sizeof(bf16_t));        // 20.48 MB (nrm*h)
  bf16_t* Acat   = (bf16_t*)alloc((size_t)NN * 1024 * sizeof(bf16_t));  // 40.96 MB
  bf16_t* BW0    = (bf16_t*)alloc((size_t)512 * 512 * sizeof(bf16_t));
  bf16_t* BT1    = (bf16_t*)alloc((size_t)512 * 1024 * sizeof(bf16_t));
  bf16_t* BT2    = (bf16_t*)alloc((size_t)512 * 1024 * sizeof(bf16_t));
  int*    cnt    = (int*)alloc((size_t)NN * sizeof(int));
  int*    esrc   = (int*)alloc(((size_t)NN * CAP + 64) * sizeof(int)); // 7.68 MB + pad

  // 1. fused prep: featb/BW0/BT1/BT2 reformats + cnt zero + esrc zero
  prep_kernel<<<PREP_BLOCKS, 256, 0, stream>>>(feat, fc_w, w1_1, w2_1, w1_2, w2_2,
                                               featb, BW0, BT1, BT2, cnt, esrc);
  // 2. bucket build (counts + slots in one pass)
  bucket_kernel<<<(EE + 255) / 256, 256, 0, stream>>>(src, dst, cnt, esrc, EE);

  // 313 m-tiles of 64 rows, 4 n-tiles; swizzled grid covers m<320 -> 1280 blocks
  // 3. h = feat @ fc_w^T + fc_b -> Acat h-half (raw) + hs (nrm*h)
  gemm_kernel<0><<<1280, 256, 0, stream>>>(featb, BW0, 512, 512, 512, NN, fc_b,
                                           nullptr, 0.0f, nullptr, hs, Acat, cnt);

  // ---- layer 1 ----
  aggregate_kernel<<<NN / 4, 256, 0, stream>>>(hs, cnt, esrc, Acat);
  gemm_kernel<1><<<1280, 256, 0, stream>>>(Acat, BT1, 1024, 1024, 1024, NN, b_1,
                                           Acat, BETA1, nullptr, res_bf, nullptr, cnt);

  // ---- layer 2 ----
  aggregate_kernel<<<NN / 4, 256, 0, stream>>>(res_bf, cnt, esrc, Acat);
  gemm_kernel<2><<<1280, 256, 0, stream>>>(Acat, BT2, 1024, 1024, 1024, NN, b_2,
                                           Acat, BETA2, out, nullptr, nullptr, nullptr);
}

// Round 12
// 336.009 us; speedup vs baseline: 1.0408x; 1.0408x over previous
//
#include <hip/hip_runtime.h>
#include <hip/hip_bf16.h>
#include <stdint.h>
#include <stddef.h>

typedef __bf16 bf16_t;
typedef __bf16 bf16x4 __attribute__((ext_vector_type(4)));
typedef __bf16 bf16x8 __attribute__((ext_vector_type(8)));
typedef float floatx4 __attribute__((ext_vector_type(4)));

#define NN 20000
#define EE 320000
#define DD 512
#define CAP 96
#define BETA1 0.6931471805599453f
#define BETA2 0.40546510810816444f

// async global->LDS, 16B per lane. LDS dest must be wave-uniform base + lane*16.
__device__ __forceinline__ void gload16(const bf16_t* g, bf16_t* l) {
  __builtin_amdgcn_global_load_lds((const __attribute__((address_space(1))) uint32_t*)g,
                                   (__attribute__((address_space(3))) uint32_t*)l, 16, 0, 0);
}

// ------- bucket fill with degree count: esrc[dst*CAP + cnt[dst]++] = src -----
__global__ __launch_bounds__(256) void bucket_kernel(
    const int* __restrict__ src, const int* __restrict__ dst,
    int* __restrict__ cnt, int* __restrict__ esrc, int E) {
  int e = blockIdx.x * 256 + threadIdx.x;
  if (e < E) {
    int d = dst[e];
    int pos = atomicAdd(&cnt[d], 1);
    if (pos < CAP) esrc[d * CAP + pos] = src[e];
  }
}

// ---------------- fused prep: zeroing + all weight/input reformats -----------
// sections by blockIdx:
//   [0, 5000)        featb: feat f32 row-major -> bf16 row-major (8 elem/thr)
//   [5000, 5128)     BW0:   fc_w f32 [n][k] -> bf16 row-major (= B^T layout)
//   [5128, 5640)     BT1:   [w1_1; 0.1*w2_1]^T via LDS 32x33 tile transpose
//   [5640, 6152)     BT2:   [w1_2; 0.1*w2_2]^T same
//   [6152, 6231)     cnt zero
//   [6231, 8106)     esrc zero (int4) — padding slots read 0 (valid node) so
//                    the aggregate ring can ALWAYS issue its gathers (fixed
//                    vmcnt counts); add-guards drop their contribution.
// 0.1 folded into the W2 half so Acat holds RAW h:
//   [f,h] @ [W1; 0.1W2]^T = f@W1 + 0.1*(h@W2)
#define PREP_BLOCKS 8106
__global__ __launch_bounds__(256) void prep_kernel(
    const float* __restrict__ feat, const float* __restrict__ fc_w,
    const float* __restrict__ w1_1, const float* __restrict__ w2_1,
    const float* __restrict__ w1_2, const float* __restrict__ w2_2,
    bf16_t* __restrict__ featb, bf16_t* __restrict__ bw0,
    bf16_t* __restrict__ bt1, bf16_t* __restrict__ bt2,
    int* __restrict__ cnt, int* __restrict__ esrc) {
  __shared__ bf16_t tile[32][33];
  int b = blockIdx.x, t = threadIdx.x;
  if (b < 5128) {
    // straight cvt, 8 f32 -> bf16x8 per thread
    const float* in = (b < 5000) ? feat : fc_w;
    bf16_t* out = (b < 5000) ? featb : bw0;
    size_t c = (size_t)(b < 5000 ? b : b - 5000) * 256 + t;
    const float* s = in + c * 8;
    float4 v0 = *(const float4*)s, v1 = *(const float4*)(s + 4);
    bf16x8 o = {(bf16_t)v0.x, (bf16_t)v0.y, (bf16_t)v0.z, (bf16_t)v0.w,
                (bf16_t)v1.x, (bf16_t)v1.y, (bf16_t)v1.z, (bf16_t)v1.w};
    *(bf16x8*)(out + c * 8) = o;
  } else if (b < 6152) {
    // BT[n][k] = scale * W[k][n] via LDS tile; 512 blocks per BT (16 x 32).
    int base = (b < 5640) ? 5128 : 5640;
    const float* Wa = (b < 5640) ? w1_1 : w1_2;
    const float* Wb = (b < 5640) ? w2_1 : w2_2;
    bf16_t* bt = (b < 5640) ? bt1 : bt2;
    int bb = b - base;
    int n0 = (bb & 15) * 32;          // n tile
    int k0 = (bb >> 4) * 32;          // k tile, [0,1024)
    int tx = t & 31, ty = t >> 5;     // 32 x 8
    const float* W = (k0 < 512) ? Wa : Wb;
    float sc = (k0 < 512) ? 1.0f : 0.1f;
    int kk = k0 & 511;
#pragma unroll
    for (int i = 0; i < 32; i += 8)
      tile[ty + i][tx] = (bf16_t)(sc * W[(size_t)(kk + ty + i) * 512 + n0 + tx]);
    __syncthreads();
#pragma unroll
    for (int i = 0; i < 32; i += 8)
      bt[(size_t)(n0 + ty + i) * 1024 + k0 + tx] = tile[tx][ty + i];
  } else if (b < 6231) {
    int i = (b - 6152) * 256 + t;
    if (i < NN) cnt[i] = 0;
  } else {
    int i = (b - 6231) * 256 + t;     // 480000 int4 = NN*CAP ints exactly
    ((int4*)esrc)[i] = make_int4(0, 0, 0, 0);
  }
}

// ---------- bucket aggregate: one wave per dst node, LDS-DMA gather ring -----
// f = 0.9 * rsqrt(deg[node]) * sum_e hs[src_e]        (hs pre-scaled by nrm)
// Acat[node][0:512] = bf16(f)   (h-half of Acat untouched, layer-invariant)
// ROUND-10 VERBATIM (best measured: total 342.6). 2-buf ring, 32KB -> 4-5
// blocks/CU. Round-11's 3-buf (48KB) regressed: the loop is L2/L3-BW-bound
// (~7 TB/s effective), so deeper MLP gains nothing while lost TLP costs.
// Fixed issue order per chunk c (fenced by "memory"-clobber waits):
//   [entering: idx(c+1) 1 op (oldest), ring(c) 4 ops]
//   vmcnt(4) -> idx(c+1) ready | issue idx(c+2) | issue ring(c+1) (4)
//   vmcnt(5) -> ring(c) landed | consume + guarded adds
// Issues are NEVER guarded out (offsets clamped, esrc zero-padded) so the
// counts are exact; per-edge guards keep the math correct.
__global__ __launch_bounds__(256) void aggregate_kernel(
    const bf16_t* __restrict__ hs, const int* __restrict__ cnt,
    const int* __restrict__ esrc, bf16_t* __restrict__ Acat) {
  __shared__ bf16_t ring[4][2][4][512];   // 4 waves x 2 bufs x 4 slots x 1KB = 32KB
  const int w = threadIdx.x >> 6;
  const int lane = threadIdx.x & 63;
  const int node = blockIdx.x * 4 + w;    // grid 5000 x 4 waves = 20000 exact
  const int* eb = esrc + (size_t)node * CAP;
  int ncnt = cnt[node];
  int n_e = ncnt < CAP ? ncnt : CAP;
  float nd = 0.9f * rsqrtf(fmaxf((float)ncnt, 1.0f));
  int nchunks = (n_e + 3) >> 2;

  float acc[8] = {};
  bf16_t* r0base = &ring[w][0][0][lane * 8];
  bf16_t* r1base = &ring[w][1][0][lane * 8];

  int4 icur, inext;

  // clean slate: cnt load retired before pipeline counting starts
  asm volatile("s_waitcnt vmcnt(0)" ::: "memory");
  __builtin_amdgcn_sched_barrier(0);
  icur = *(const int4*)(eb);                   // idx(0)
  asm volatile("s_waitcnt vmcnt(0)" ::: "memory");
  __builtin_amdgcn_sched_barrier(0);
  inext = *(const int4*)(eb + 4);              // idx(1)  [issued BEFORE ring(0)]
  gload16(hs + (size_t)icur.x * DD + lane * 8, r0base);
  gload16(hs + (size_t)icur.y * DD + lane * 8, r0base + 512);
  gload16(hs + (size_t)icur.z * DD + lane * 8, r0base + 1024);
  gload16(hs + (size_t)icur.w * DD + lane * 8, r0base + 1536);

  for (int c = 0; c < nchunks; ++c) {
    // retire idx(c+1) (oldest); ring(c) stays in flight
    asm volatile("s_waitcnt vmcnt(4)" ::: "memory");
    __builtin_amdgcn_sched_barrier(0);
    int4 iuse = inext;
    int off2 = (c + 2) * 4; off2 = off2 > CAP - 4 ? CAP - 4 : off2;
    inext = *(const int4*)(eb + off2);         // idx(c+2): 1 op
    bf16_t* rbn = ((c + 1) & 1) ? r1base : r0base;
    gload16(hs + (size_t)iuse.x * DD + lane * 8, rbn);
    gload16(hs + (size_t)iuse.y * DD + lane * 8, rbn + 512);
    gload16(hs + (size_t)iuse.z * DD + lane * 8, rbn + 1024);
    gload16(hs + (size_t)iuse.w * DD + lane * 8, rbn + 1536);
    // retire ring(c) (oldest 4); keep idx(c+2) + ring(c+1) = 5 in flight
    asm volatile("s_waitcnt vmcnt(5)" ::: "memory");
    __builtin_amdgcn_sched_barrier(0);
    bf16_t* rb = (c & 1) ? r1base : r0base;
    bf16x8 v0 = *(const bf16x8*)(rb);
    bf16x8 v1 = *(const bf16x8*)(rb + 512);
    bf16x8 v2 = *(const bf16x8*)(rb + 1024);
    bf16x8 v3 = *(const bf16x8*)(rb + 1536);
    int e0 = c * 4;
    if (e0 < n_e) {
#pragma unroll
      for (int k = 0; k < 8; ++k) acc[k] += (float)v0[k];
    }
    if (e0 + 1 < n_e) {
#pragma unroll
      for (int k = 0; k < 8; ++k) acc[k] += (float)v1[k];
    }
    if (e0 + 2 < n_e) {
#pragma unroll
      for (int k = 0; k < 8; ++k) acc[k] += (float)v2[k];
    }
    if (e0 + 3 < n_e) {
#pragma unroll
      for (int k = 0; k < 8; ++k) acc[k] += (float)v3[k];
    }
  }

  bf16x8 ob;
#pragma unroll
  for (int k = 0; k < 8; ++k) ob[k] = (bf16_t)(nd * acc[k]);
  *(bf16x8*)(Acat + (size_t)node * 1024 + lane * 8) = ob;
}

// -------- GEMM: C = A(MxK,bf16) @ B(Kx512), B given transposed BT[n][k] ------
// Round-2 verified structure (best of 7 variants tried): tile 64x128, 4 waves
// (2x2, 32x64 each), BK=64, 2-buf LDS via global_load_lds, 1 barrier/iter,
// 48KB LDS -> 3 blocks/CU. DO NOT TOUCH (rounds 1,3,4,5,6,8 all regressed).
// Swizzle for 128B rows: stored chunk cc = global chunk gc ^ (row&7).
// XCD swizzle: bIdx = (m%8) + 8*(n + 4*(m/8)).
// MODE 0: h = acc+bias -> acat2[row*1024+512+col]=bf16(h) (raw, for f0) AND
//         outb[row*512+col] = bf16(nrm_row*h)  (hs: pre-scaled aggregate input)
// MODE 1: fs = Acat[row][col] + 0.1*Acat[row][512+col];
//         r = relu((1-beta)*fs + beta*acc + bias);
//         outb[idx] = bf16(nrm_row*r)          (res': pre-scaled agg-2 input)
// MODE 2: same r -> outf[idx] = r (f32 final output)
template <int MODE>
__global__ __launch_bounds__(256) void gemm_kernel(
    const bf16_t* __restrict__ A, const bf16_t* __restrict__ BT,
    int lda, int ldb, int K, int M,
    const float* __restrict__ bias,
    const bf16_t* __restrict__ acat_ro, float beta,
    float* __restrict__ outf, bf16_t* __restrict__ outb,
    bf16_t* __restrict__ acat2,
    const int* __restrict__ cnt) {
  __shared__ bf16_t As[2][64 * 64];    // 8 KB per buf
  __shared__ bf16_t Bs[2][128 * 64];   // 16 KB per buf

  const int bid = blockIdx.x;
  const int mt = (bid >> 5) * 8 + (bid & 7);   // m-tile
  const int nt = (bid >> 3) & 3;               // n-tile
  const int m0 = mt * 64;
  if (m0 >= M) return;
  const int n0 = nt * 128;

  const int t = threadIdx.x;
  const int lane = t & 63;
  const int w = t >> 6;
  const int wm = w & 1, wn = w >> 1;
  const int quad = lane >> 4, m16 = lane & 15;

  // staging: LDS-linear chunk c_l -> row r=c_l>>3, slot cc=c_l&7 holds global
  // chunk gc = cc ^ (r&7). Thread t stages c_l = t (+256 [+512 +768 for B]).
  const int tr = t >> 3;
  const int gc = (t & 7) ^ (tr & 7);
  int arow0 = m0 + tr;      arow0 = arow0 < M ? arow0 : M - 1;  // clamp OOB
  int arow1 = m0 + tr + 32; arow1 = arow1 < M ? arow1 : M - 1;
  const bf16_t* agp0 = A + (size_t)arow0 * lda + gc * 8;
  const bf16_t* agp1 = A + (size_t)arow1 * lda + gc * 8;
  const bf16_t* bgp0 = BT + (size_t)(n0 + tr) * ldb + gc * 8;
  const bf16_t* bgp1 = BT + (size_t)(n0 + tr + 32) * ldb + gc * 8;
  const bf16_t* bgp2 = BT + (size_t)(n0 + tr + 64) * ldb + gc * 8;
  const bf16_t* bgp3 = BT + (size_t)(n0 + tr + 96) * ldb + gc * 8;

#define STAGE(buf, ko)                              \
  gload16(agp0 + (ko), &As[buf][t * 8]);            \
  gload16(agp1 + (ko), &As[buf][(t + 256) * 8]);    \
  gload16(bgp0 + (ko), &Bs[buf][t * 8]);            \
  gload16(bgp1 + (ko), &Bs[buf][(t + 256) * 8]);    \
  gload16(bgp2 + (ko), &Bs[buf][(t + 512) * 8]);    \
  gload16(bgp3 + (ko), &Bs[buf][(t + 768) * 8]);

  floatx4 acc[2][4] = {};
  const int niter = K >> 6;

  // stage buffer 0
  STAGE(0, 0)

  for (int kt = 0; kt < niter; ++kt) {
    __syncthreads();   // drains buf kt's loads (issued one iter ago)
    const int b = kt & 1;
    if (kt + 1 < niter) {        // prefetch next buffer during compute
      const int ko = (kt + 1) * 64;
      STAGE(b ^ 1, ko)
    }

#pragma unroll
    for (int ks = 0; ks < 2; ++ks) {
      bf16x8 af[2], bfr[4];
#pragma unroll
      for (int i = 0; i < 2; ++i) {
        int arow = wm * 32 + i * 16 + m16;
        int cc = (ks * 4 + quad) ^ (arow & 7);
        af[i] = *(const bf16x8*)(&As[b][(arow * 8 + cc) * 8]);
      }
#pragma unroll
      for (int j = 0; j < 4; ++j) {
        int brow = wn * 64 + j * 16 + m16;
        int cc = (ks * 4 + quad) ^ (brow & 7);
        bfr[j] = *(const bf16x8*)(&Bs[b][(brow * 8 + cc) * 8]);
      }
#pragma unroll
      for (int i = 0; i < 2; ++i)
#pragma unroll
        for (int j = 0; j < 4; ++j)
          acc[i][j] = __builtin_amdgcn_mfma_f32_16x16x32_bf16(af[i], bfr[j], acc[i][j], 0, 0, 0);
    }
  }
#undef STAGE

  // per-thread row rsqrt(cnt) (MODE 0/1 pre-scale writes). 8 unique rows.
  float rsv[2][4];
  if constexpr (MODE != 2) {
#pragma unroll
    for (int i = 0; i < 2; ++i)
#pragma unroll
      for (int p = 0; p < 4; ++p) {
        int row = m0 + wm * 32 + i * 16 + quad * 4 + p;
        int rowc = row < M ? row : M - 1;
        rsv[i][p] = rsqrtf(fmaxf((float)cnt[rowc], 1.0f));
      }
  }

  // epilogue: C/D layout col = lane&15, row = quad*4 + reg
#pragma unroll
  for (int i = 0; i < 2; ++i) {
#pragma unroll
    for (int j = 0; j < 4; ++j) {
      int col = n0 + wn * 64 + j * 16 + m16;
      float bv = bias[col];
#pragma unroll
      for (int p = 0; p < 4; ++p) {
        int row = m0 + wm * 32 + i * 16 + quad * 4 + p;
        if (row < M) {
          float v = acc[i][j][p];
          if constexpr (MODE == 0) {
            float hv = v + bv;
            acat2[(size_t)row * 1024 + 512 + col] = (bf16_t)hv;        // raw h (f0)
            outb[(size_t)row * DD + col] = (bf16_t)(rsv[i][p] * hv);   // hs
          } else {
            size_t idx = (size_t)row * DD + col;
            float fsv = (float)acat_ro[(size_t)row * 1024 + col] +
                        0.1f * (float)acat_ro[(size_t)row * 1024 + 512 + col];
            float r = (1.0f - beta) * fsv + beta * v + bv;
            r = fmaxf(r, 0.0f);
            if constexpr (MODE == 1) outb[idx] = (bf16_t)(rsv[i][p] * r);  // res'
            else outf[idx] = r;
          }
        }
      }
    }
  }
}

extern "C" void kernel_launch(void* const* d_in, const int* in_sizes, int n_in,
                              void* d_out, int out_size, void* d_ws, size_t ws_size,
                              hipStream_t stream) {
  const float* feat = (const float*)d_in[0];
  const int* src = (const int*)d_in[1];
  const int* dst = (const int*)d_in[2];
  const float* fc_w = (const float*)d_in[3];
  const float* fc_b = (const float*)d_in[4];
  const float* w1_1 = (const float*)d_in[5];
  const float* w2_1 = (const float*)d_in[6];
  const float* b_1  = (const float*)d_in[7];
  const float* w1_2 = (const float*)d_in[8];
  const float* w2_2 = (const float*)d_in[9];
  const float* b_2  = (const float*)d_in[10];
  float* out = (float*)d_out;

  char* ws = (char*)d_ws;
  size_t off = 0;
  auto alloc = [&](size_t bytes) {
    char* p = ws + off;
    off += (bytes + 255) & ~(size_t)255;
    return p;
  };
  const size_t NDf = (size_t)NN * DD;               // 10.24M elements
  bf16_t* res_bf = (bf16_t*)alloc(NDf * sizeof(bf16_t));        // 20.48 MB (nrm*res)
  bf16_t* featb  = (bf16_t*)alloc(NDf * sizeof(bf16_t));        // 20.48 MB
  bf16_t* hs     = (bf16_t*)alloc(NDf * sizeof(bf16_t));        // 20.48 MB (nrm*h)
  bf16_t* Acat   = (bf16_t*)alloc((size_t)NN * 1024 * sizeof(bf16_t));  // 40.96 MB
  bf16_t* BW0    = (bf16_t*)alloc((size_t)512 * 512 * sizeof(bf16_t));
  bf16_t* BT1    = (bf16_t*)alloc((size_t)512 * 1024 * sizeof(bf16_t));
  bf16_t* BT2    = (bf16_t*)alloc((size_t)512 * 1024 * sizeof(bf16_t));
  int*    cnt    = (int*)alloc((size_t)NN * sizeof(int));
  int*    esrc   = (int*)alloc(((size_t)NN * CAP + 64) * sizeof(int)); // 7.68 MB + pad

  // 1. fused prep: featb/BW0/BT1/BT2 reformats + cnt zero + esrc zero
  prep_kernel<<<PREP_BLOCKS, 256, 0, stream>>>(feat, fc_w, w1_1, w2_1, w1_2, w2_2,
                                               featb, BW0, BT1, BT2, cnt, esrc);
  // 2. bucket build (counts + slots in one pass)
  bucket_kernel<<<(EE + 255) / 256, 256, 0, stream>>>(src, dst, cnt, esrc, EE);

  // 313 m-tiles of 64 rows, 4 n-tiles; swizzled grid covers m<320 -> 1280 blocks
  // 3. h = feat @ fc_w^T + fc_b -> Acat h-half (raw) + hs (nrm*h)
  gemm_kernel<0><<<1280, 256, 0, stream>>>(featb, BW0, 512, 512, 512, NN, fc_b,
                                           nullptr, 0.0f, nullptr, hs, Acat, cnt);

  // ---- layer 1 ----
  aggregate_kernel<<<NN / 4, 256, 0, stream>>>(hs, cnt, esrc, Acat);
  gemm_kernel<1><<<1280, 256, 0, stream>>>(Acat, BT1, 1024, 1024, 1024, NN, b_1,
                                           Acat, BETA1, nullptr, res_bf, nullptr, cnt);

  // ---- layer 2 ----
  aggregate_kernel<<<NN / 4, 256, 0, stream>>>(res_bf, cnt, esrc, Acat);
  gemm_kernel<2><<<1280, 256, 0, stream>>>(Acat, BT2, 1024, 1024, 1024, NN, b_2,
                                           Acat, BETA2, out, nullptr, nullptr, nullptr);
}